// Round 1
// baseline (872.273 us; speedup 1.0000x reference)
//
#include <hip/hip_runtime.h>
#include <math.h>

// ---------------------------------------------------------------------------
// Problem constants
// ---------------------------------------------------------------------------
#define BATCH 2048
#define NRIS  100
#define MN    16
#define DIN   303
#define DOUT  264   // 200 + 4*16
// THRESH_W = 1e-15  -> CCC = quad * 1e15f

// ---------------------------------------------------------------------------
// async 16B global->LDS DMA (wave-uniform LDS base + lane*16 semantics)
// ---------------------------------------------------------------------------
__device__ __forceinline__ void gload_lds16(const float* g, float* lds) {
    __builtin_amdgcn_global_load_lds(
        (const __attribute__((address_space(1))) unsigned int*)g,
        (__attribute__((address_space(3))) unsigned int*)lds, 16, 0, 0);
}

// ---------------------------------------------------------------------------
// Pipelined fp32 GEMM: C[M,N] = act(A[M,K] @ W[K,N] + bias[N])
// Template: BM in {64,128}, BK=16, 256 threads, micro-tile (BM/16) x TN,
// BN = 16*TN (TN=8 or 4). Double-buffered LDS; A staged via registers,
// B via global_load_lds DMA.
// Grid sizing rationale (256 CUs): 64x64 tiles give 256-512 blocks for the
// MLP shapes -> 2 blocks/CU (8 waves/CU, 2 waves/SIMD) instead of the old
// 128x128 config's 128 blocks (half the CUs idle, 1 wave/SIMD).
// Requires: M%BM==0, N%BN==0 (full tiles). K arbitrary (A zero-fills OOB k;
// B clamps address, A-zero kills product).
// VECA: A rows 16B-aligned & K%4==0 -> float4 A staging.
// ---------------------------------------------------------------------------
template <int BM, int BN, int TN, bool RELU, bool VECA>
__global__ __launch_bounds__(256) void gemm_pipe(
    const float* __restrict__ A, const float* __restrict__ W,
    const float* __restrict__ bias, float* __restrict__ C,
    int M, int N, int K)
{
    constexpr int MR  = BM / 16;   // micro rows per thread (8 or 4)
    constexpr int MH  = MR / 4;    // 4-row chunks (2 or 1)
    constexpr int AF4 = BM / 64;   // float4 A-stage loads per thread (2 or 1)

    __shared__ __align__(16) float As[2][16][BM + 4];  // pad +4: 2-way conflicts only
    __shared__ __align__(16) float Bs[2][16][BN];      // DMA target (contiguous)

    const int tid = threadIdx.x;
    const int tx  = tid & 15;    // col group
    const int ty  = tid >> 4;    // row group (0..15)
    const int w   = tid >> 6;    // wave id (uniform per wave)
    const int l   = tid & 63;
    const int bm  = blockIdx.x * BM;
    const int bn  = blockIdx.y * BN;

    const int nt = (K + 15) / 16;

    // ---- A staging state ----
    float areg[MR];
    // scalar path mapping
    const int la_k = tid & 15;
    const int la_m = tid >> 4;
    // vector path mapping: f4 index: r=row within 64-row chunk, q=k-quad
    const int va_r0 = tid >> 2;        // rows 0..63
    const int va_q  = tid & 3;

    auto loadA = [&](int k0) {
        if (VECA) {
#pragma unroll
            for (int h = 0; h < AF4; ++h) {
                const float4* p =
                    (const float4*)(A + (size_t)(bm + h * 64 + va_r0) * K + k0 + 4 * va_q);
                float4 v = *p;
                areg[4 * h + 0] = v.x; areg[4 * h + 1] = v.y;
                areg[4 * h + 2] = v.z; areg[4 * h + 3] = v.w;
            }
        } else {
            int gk = k0 + la_k;
            bool ok = gk < K;
#pragma unroll
            for (int p = 0; p < MR; ++p) {
                int m = la_m + 16 * p;
                areg[p] = ok ? A[(size_t)(bm + m) * K + gk] : 0.f;
            }
        }
    };
    auto writeA = [&](int buf) {
        if (VECA) {
#pragma unroll
            for (int h = 0; h < AF4; ++h)
#pragma unroll
                for (int j = 0; j < 4; ++j)
                    As[buf][4 * va_q + j][h * 64 + va_r0] = areg[4 * h + j];
        } else {
#pragma unroll
            for (int p = 0; p < MR; ++p)
                As[buf][la_k][la_m + 16 * p] = areg[p];
        }
    };
    auto issueB = [&](int k0, int buf) {
        // tile = 16 x BN floats = 4*BN float4s; one DMA inst covers 64 f4s/wave
#pragma unroll
        for (int c = 0; c < (4 * BN) / 256; ++c) {
            int gbase = c * 256 + w * 64;          // wave-uniform f4 base
            int g  = gbase + l;
            int k  = g / (BN / 4);
            int n4 = g % (BN / 4);
            int gk = k0 + k; if (gk > K - 1) gk = K - 1;   // clamp; A=0 kills it
            gload_lds16(W + (size_t)gk * N + bn + 4 * n4,
                        &Bs[buf][0][0] + (size_t)gbase * 4);
        }
    };

    float acc[MR][TN];
#pragma unroll
    for (int i = 0; i < MR; ++i)
#pragma unroll
        for (int j = 0; j < TN; ++j) acc[i][j] = 0.f;

    // ---- prologue: tile 0 -> buf 0 ----
    loadA(0);
    issueB(0, 0);
    writeA(0);
    __syncthreads();

    for (int t = 0; t < nt; ++t) {
        int cur = t & 1, nxt = cur ^ 1;
        if (t + 1 < nt) {
            loadA((t + 1) * 16);
            issueB((t + 1) * 16, nxt);
        }
        // compute on buf[cur]
#pragma unroll
        for (int kk = 0; kk < 16; ++kk) {
            const float* as = &As[cur][kk][0];
            const float* bs = &Bs[cur][kk][0];
            float a_[MR];
#pragma unroll
            for (int h = 0; h < MH; ++h) {
                float4 a4 = *(const float4*)(as + h * 64 + ty * 4);
                a_[4 * h + 0] = a4.x; a_[4 * h + 1] = a4.y;
                a_[4 * h + 2] = a4.z; a_[4 * h + 3] = a4.w;
            }
            float b_[TN];
            float4 b0 = *(const float4*)(bs + tx * 4);
            b_[0] = b0.x; b_[1] = b0.y; b_[2] = b0.z; b_[3] = b0.w;
            if (TN == 8) {
                float4 b1 = *(const float4*)(bs + 64 + tx * 4);
                b_[4] = b1.x; b_[5] = b1.y; b_[6] = b1.z; b_[7] = b1.w;
            }
#pragma unroll
            for (int i = 0; i < MR; ++i)
#pragma unroll
                for (int j = 0; j < TN; ++j)
                    acc[i][j] = fmaf(a_[i], b_[j], acc[i][j]);
        }
        if (t + 1 < nt) writeA(nxt);
        __syncthreads();
    }

    // ---- epilogue ----
    float4 bb0 = *(const float4*)&bias[bn + tx * 4];
    float4 bb1;
    if (TN == 8) bb1 = *(const float4*)&bias[bn + 64 + tx * 4];
    float bbs[8] = {bb0.x, bb0.y, bb0.z, bb0.w,
                    (TN == 8) ? bb1.x : 0.f, (TN == 8) ? bb1.y : 0.f,
                    (TN == 8) ? bb1.z : 0.f, (TN == 8) ? bb1.w : 0.f};
#pragma unroll
    for (int h = 0; h < MH; ++h) {
#pragma unroll
        for (int i = 0; i < 4; ++i) {
            int gm = bm + h * 64 + ty * 4 + i;
            int ri = h * 4 + i;
            float4 v;
            v.x = acc[ri][0] + bbs[0]; v.y = acc[ri][1] + bbs[1];
            v.z = acc[ri][2] + bbs[2]; v.w = acc[ri][3] + bbs[3];
            if (RELU) {
                v.x = fmaxf(v.x, 0.f); v.y = fmaxf(v.y, 0.f);
                v.z = fmaxf(v.z, 0.f); v.w = fmaxf(v.w, 0.f);
            }
            *(float4*)&C[(size_t)gm * N + bn + tx * 4] = v;
            if (TN == 8) {
                float4 u;
                u.x = acc[ri][4] + bbs[4]; u.y = acc[ri][5] + bbs[5];
                u.z = acc[ri][6] + bbs[6]; u.w = acc[ri][7] + bbs[7];
                if (RELU) {
                    u.x = fmaxf(u.x, 0.f); u.y = fmaxf(u.y, 0.f);
                    u.z = fmaxf(u.z, 0.f); u.w = fmaxf(u.w, 0.f);
                }
                *(float4*)&C[(size_t)gm * N + bn + 64 + tx * 4] = u;
            }
        }
    }
}

// ---------------------------------------------------------------------------
// Legacy 64x64 GEMM (used only for GEMM4: N=264 ragged, 0.55 GFLOP)
// ---------------------------------------------------------------------------
template <bool RELU>
__global__ __launch_bounds__(256) void gemm_kernel(
    const float* __restrict__ A, const float* __restrict__ W,
    const float* __restrict__ bias, float* __restrict__ C,
    int M, int N, int K)
{
    __shared__ __align__(16) float As[16][68];
    __shared__ __align__(16) float Bs[16][68];

    const int tid = threadIdx.x;
    const int tx  = tid & 15;
    const int ty  = tid >> 4;
    const int bm  = blockIdx.x * 64;
    const int bn  = blockIdx.y * 64;

    const int la_k = tid & 15;
    const int la_m = tid >> 4;
    const int lb_n = tid & 63;
    const int lb_k = tid >> 6;

    float acc[4][4];
#pragma unroll
    for (int i = 0; i < 4; ++i)
#pragma unroll
        for (int j = 0; j < 4; ++j) acc[i][j] = 0.f;

    for (int k0 = 0; k0 < K; k0 += 16) {
#pragma unroll
        for (int p = 0; p < 4; ++p) {
            int m  = la_m + p * 16;
            int gk = k0 + la_k;
            float v = 0.f;
            if (gk < K) v = A[(size_t)(bm + m) * K + gk];
            As[la_k][m] = v;
        }
#pragma unroll
        for (int p = 0; p < 4; ++p) {
            int k  = lb_k + p * 4;
            int gk = k0 + k;
            int gn = bn + lb_n;
            float v = 0.f;
            if (gk < K && gn < N) v = W[(size_t)gk * N + gn];
            Bs[k][lb_n] = v;
        }
        __syncthreads();
#pragma unroll
        for (int kk = 0; kk < 16; ++kk) {
            float4 a4 = *(const float4*)&As[kk][ty * 4];
            float4 b4 = *(const float4*)&Bs[kk][tx * 4];
            float a_[4] = {a4.x, a4.y, a4.z, a4.w};
            float b_[4] = {b4.x, b4.y, b4.z, b4.w};
#pragma unroll
            for (int i = 0; i < 4; ++i)
#pragma unroll
                for (int j = 0; j < 4; ++j)
                    acc[i][j] = fmaf(a_[i], b_[j], acc[i][j]);
        }
        __syncthreads();
    }

    if (bn + 64 <= N) {
        float4 bb = *(const float4*)&bias[bn + tx * 4];
#pragma unroll
        for (int i = 0; i < 4; ++i) {
            int gm = bm + ty * 4 + i;
            float4 v;
            v.x = acc[i][0] + bb.x; v.y = acc[i][1] + bb.y;
            v.z = acc[i][2] + bb.z; v.w = acc[i][3] + bb.w;
            if (RELU) {
                v.x = fmaxf(v.x, 0.f); v.y = fmaxf(v.y, 0.f);
                v.z = fmaxf(v.z, 0.f); v.w = fmaxf(v.w, 0.f);
            }
            *(float4*)&C[(size_t)gm * N + bn + tx * 4] = v;
        }
    } else {
#pragma unroll
        for (int i = 0; i < 4; ++i) {
            int gm = bm + ty * 4 + i;
#pragma unroll
            for (int j = 0; j < 4; ++j) {
                int gn = bn + tx * 4 + j;
                if (gn < N) {
                    float v = acc[i][j] + bias[gn];
                    if (RELU) v = fmaxf(v, 0.f);
                    C[(size_t)gm * N + gn] = v;
                }
            }
        }
    }
}

// ---------------------------------------------------------------------------
// theta_prep: unit-modulus theta -> thU; F1/F2 normalization -> out[200:264]
// ---------------------------------------------------------------------------
__global__ __launch_bounds__(128) void theta_prep_kernel(
    const float* __restrict__ th1, float* __restrict__ thU,
    float* __restrict__ out)
{
    int b   = blockIdx.x;
    int tid = threadIdx.x;
    const float* row = th1 + (size_t)b * DOUT;
    __shared__ float sc[2];

    if (tid == 112) {
        float s = 0.f;
        for (int j = 0; j < MN; ++j) {
            float fr = row[200 + j], fi = row[200 + MN + j];
            s += fr * fr + fi * fi;
        }
        sc[0] = sqrtf(2.f / s);
    } else if (tid == 113) {
        float s = 0.f;
        for (int j = 0; j < MN; ++j) {
            float fr = row[200 + 2 * MN + j], fi = row[200 + 3 * MN + j];
            s += fr * fr + fi * fi;
        }
        sc[1] = sqrtf(2.f / s);
    }

    if (tid < NRIS) {
        float re = row[tid], im = row[NRIS + tid];
        float r  = sqrtf(re * re + im * im);
        thU[(size_t)b * 200 + tid]        = re / r;
        thU[(size_t)b * 200 + NRIS + tid] = im / r;
    }
    __syncthreads();
    if (tid < 32) {
        int j = tid & 15, h = tid >> 4;
        out[(size_t)b * DOUT + 200 + h * MN + j]          = row[200 + h * MN + j] * sc[0];
        out[(size_t)b * DOUT + 200 + 2 * MN + h * MN + j] = row[200 + 2 * MN + h * MN + j] * sc[1];
    }
}

// ---------------------------------------------------------------------------
// quad: one block per (b,c). quad[bc] = Re(theta^H T theta). 655 MB stream.
// ---------------------------------------------------------------------------
__global__ __launch_bounds__(256) void quad_kernel(
    const float* __restrict__ Tr, const float* __restrict__ Ti,
    const float* __restrict__ thU, float* __restrict__ quad)
{
    int bc = blockIdx.x;
    int b  = bc >> 2;
    int tid = threadIdx.x;

    __shared__ __align__(16) float sA[NRIS];
    __shared__ __align__(16) float sB[NRIS];
    if (tid < 200) {
        float v = thU[(size_t)b * 200 + tid];
        if (tid < NRIS) sA[tid] = v;
        else            sB[tid - NRIS] = v;
    }
    __syncthreads();

    const float4* R4 = (const float4*)(Tr + (size_t)bc * (NRIS * NRIS));
    const float4* I4 = (const float4*)(Ti + (size_t)bc * (NRIS * NRIS));

    float acc = 0.f;
    for (int j = tid; j < 2500; j += 256) {
        int n  = j / 25;
        int mb = (j - n * 25) * 4;
        float4 r  = R4[j];
        float4 im = I4[j];
        float an = sA[n], bn = sB[n];
        float4 am = *(const float4*)&sA[mb];
        float4 bm = *(const float4*)&sB[mb];
        acc += r.x * (an * am.x + bn * bm.x) + im.x * (bn * am.x - an * bm.x);
        acc += r.y * (an * am.y + bn * bm.y) + im.y * (bn * am.y - an * bm.y);
        acc += r.z * (an * am.z + bn * bm.z) + im.z * (bn * am.z - an * bm.z);
        acc += r.w * (an * am.w + bn * bm.w) + im.w * (bn * am.w - an * bm.w);
    }

    for (int off = 32; off > 0; off >>= 1) acc += __shfl_down(acc, off, 64);
    __shared__ float wsum[4];
    int wave = tid >> 6, lane = tid & 63;
    if (lane == 0) wsum[wave] = acc;
    __syncthreads();
    if (tid == 0) quad[bc] = wsum[0] + wsum[1] + wsum[2] + wsum[3];
}

// ---------------------------------------------------------------------------
// finalize: scale = rsqrt(max(max_c(quad*1e15), 1)); out[b][0:200] = thU*scale
// ---------------------------------------------------------------------------
__global__ __launch_bounds__(128) void finalize_kernel(
    const float* __restrict__ thU, const float* __restrict__ quad,
    float* __restrict__ out)
{
    int b   = blockIdx.x;
    int tid = threadIdx.x;
    __shared__ float sc;
    if (tid == 0) {
        const float* q = quad + (size_t)b * 4;
        float mx = fmaxf(fmaxf(q[0], q[1]), fmaxf(q[2], q[3])) * 1e15f;
        sc = 1.f / sqrtf(fmaxf(mx, 1.0f));
    }
    __syncthreads();
    if (tid < NRIS) {
        out[(size_t)b * DOUT + tid]        = thU[(size_t)b * 200 + tid] * sc;
        out[(size_t)b * DOUT + NRIS + tid] = thU[(size_t)b * 200 + NRIS + tid] * sc;
    }
}

// ---------------------------------------------------------------------------
// launch
// ---------------------------------------------------------------------------
extern "C" void kernel_launch(void* const* d_in, const int* in_sizes, int n_in,
                              void* d_out, int out_size, void* d_ws, size_t ws_size,
                              hipStream_t stream)
{
    const float* sample1 = (const float*)d_in[0];
    const float* T_real  = (const float*)d_in[1];
    const float* T_imag  = (const float*)d_in[2];
    const float* W1 = (const float*)d_in[3];
    const float* b1 = (const float*)d_in[4];
    const float* W2 = (const float*)d_in[5];
    const float* b2 = (const float*)d_in[6];
    const float* W3 = (const float*)d_in[7];
    const float* b3 = (const float*)d_in[8];
    const float* W4 = (const float*)d_in[9];
    const float* b4 = (const float*)d_in[10];
    float* out = (float*)d_out;

    float* ws   = (float*)d_ws;
    float* h1   = ws;                                   // 2048*1024
    float* h2   = ws + (size_t)BATCH * 1024;            // 2048*1024
    float* h3   = ws;                                   // 2048*512 (reuse h1)
    float* th1  = ws + (size_t)2 * BATCH * 1024;        // 2048*264
    float* thU  = th1 + (size_t)BATCH * DOUT;           // 2048*200
    float* quad = thU + (size_t)BATCH * 200;            // 2048*4

    dim3 blk(256);
    // GEMM1: 303 -> 1024 (K=303: scalar A staging). 512 blocks (2/CU).
    gemm_pipe<64, 64, 4, true, false><<<dim3(BATCH / 64, 1024 / 64), blk, 0, stream>>>(
        sample1, W1, b1, h1, BATCH, 1024, DIN);
    // GEMM2: 1024 -> 1024. 512 blocks (2/CU).
    gemm_pipe<64, 64, 4, true, true><<<dim3(BATCH / 64, 1024 / 64), blk, 0, stream>>>(
        h1, W2, b2, h2, BATCH, 1024, 1024);
    // GEMM3: 1024 -> 512. 256 blocks (1/CU, full machine).
    gemm_pipe<64, 64, 4, true, true><<<dim3(BATCH / 64, 512 / 64), blk, 0, stream>>>(
        h2, W3, b3, h3, BATCH, 512, 1024);
    // GEMM4: 512 -> 264 (ragged N, legacy kernel)
    gemm_kernel<false><<<dim3(BATCH / 64, (DOUT + 63) / 64), blk, 0, stream>>>(
        h3, W4, b4, th1, BATCH, DOUT, 512);

    theta_prep_kernel<<<dim3(BATCH), dim3(128), 0, stream>>>(th1, thU, out);
    quad_kernel<<<dim3(BATCH * 4), dim3(256), 0, stream>>>(T_real, T_imag, thU, quad);
    finalize_kernel<<<dim3(BATCH), dim3(128), 0, stream>>>(thU, quad, out);
}

// Round 2
// 759.921 us; speedup vs baseline: 1.1478x; 1.1478x over previous
//
#include <hip/hip_runtime.h>
#include <math.h>

// ---------------------------------------------------------------------------
// Problem constants
// ---------------------------------------------------------------------------
#define BATCH 2048
#define NRIS  100
#define MN    16
#define DIN   303
#define DOUT  264   // 200 + 4*16
#define TH1_LD 320  // padded row stride of th1 (N of GEMM4 padded to mult of 64)
// THRESH_W = 1e-15 -> CCC = quad * 1e15f

typedef short     bf16x8 __attribute__((ext_vector_type(8)));
typedef float     f32x4  __attribute__((ext_vector_type(4)));
typedef unsigned short u16;

// f32 -> bf16 (round-nearest-even), as raw u16
__device__ __forceinline__ u16 f2bf(float x) {
    unsigned u = __float_as_uint(x);
    unsigned r = (u + 0x7fffu + ((u >> 16) & 1u)) >> 16;
    return (u16)r;
}
__device__ __forceinline__ float bf2f(u16 h) {
    return __uint_as_float(((unsigned)h) << 16);
}

// async 16B global->LDS DMA (wave-uniform LDS base + lane*16 semantics)
__device__ __forceinline__ void gload_lds16(const void* g, void* lds) {
    __builtin_amdgcn_global_load_lds(
        (const __attribute__((address_space(1))) unsigned int*)g,
        (__attribute__((address_space(3))) unsigned int*)lds, 16, 0, 0);
}

// ---------------------------------------------------------------------------
// Split-bf16 MFMA GEMM:  C[M,N] = act(A @ B + bias)
//   A given as (Ahi,Alo)  [M,Kp] bf16 row-major
//   B given as (Bhi,Blo)  [N,Kp] bf16 row-major  (i.e. B^T, k-contiguous)
//   acc += ahi*bhi + ahi*blo + alo*bhi   (3x mfma_f32_16x16x32_bf16)
// 256 threads = 4 waves in 2x2; wave tile (BM/2)x(BN/2); frags 16x16.
// LDS tile rows are [64 bf16] = 8 slots of 16B: slots 0-3 = hi k0..31,
// slots 4-7 = lo k0..31, XOR-swizzled: phys_slot = logical ^ (row&7).
// Staging via global_load_lds with pre-swizzled per-lane SOURCE address
// (linear LDS dest), reads apply the same XOR -> 2-way conflicts only.
// Fragment k-mapping: lane holds 8 contiguous k (k = (lane>>4)*8 + e) for
// BOTH operands -> contraction pairing correct for any HW-internal k-order.
// C/D layout (HW-verified): col = lane&15, row = (lane>>4)*4 + reg.
// Requires M%BM==0, N%BN==0, Kp%32==0.
// ---------------------------------------------------------------------------
template <int BM, int BN, bool RELU, bool SPLIT>
__global__ __launch_bounds__(256) void gemm_bf16x3(
    const u16* __restrict__ Ahi, const u16* __restrict__ Alo,
    const u16* __restrict__ Bhi, const u16* __restrict__ Blo,
    const float* __restrict__ bias, int Nb,
    float* __restrict__ Cf, u16* __restrict__ Chi, u16* __restrict__ Clo,
    int M, int N, int Kp)
{
    constexpr int WR = BM / 2, WC = BN / 2;    // per-wave tile
    constexpr int FM = WR / 16, FN = WC / 16;  // 16x16 frags per wave
    constexpr int IA = BM / 32;                // gload insts/wave for A tile
    constexpr int IB = BN / 32;

    __shared__ __align__(16) short As[2][BM][64];
    __shared__ __align__(16) short Bs[2][BN][64];

    const int tid = threadIdx.x;
    const int w  = tid >> 6, l = tid & 63;
    const int lg = l >> 4, lx = l & 15, l7 = l & 7;
    const int bm = blockIdx.x * BM, bn = blockIdx.y * BN;
    const int wrow = (w >> 1) * WR, wcol = (w & 1) * WC;
    const int nt = Kp / 32;

    auto stage = [&](int k0, int buf) {
#pragma unroll
        for (int i = 0; i < IA; ++i) {
            int fi = (w * IA + i) * 64 + l;          // f4-slot index in tile
            int r = fi >> 3, p = fi & 7, q = p ^ (r & 7);
            const u16* src = (q < 4)
                ? Ahi + (size_t)(bm + r) * Kp + k0 + q * 8
                : Alo + (size_t)(bm + r) * Kp + k0 + (q - 4) * 8;
            gload_lds16(src, &As[buf][0][0] + (size_t)(w * IA + i) * 512);
        }
#pragma unroll
        for (int i = 0; i < IB; ++i) {
            int fi = (w * IB + i) * 64 + l;
            int r = fi >> 3, p = fi & 7, q = p ^ (r & 7);
            const u16* src = (q < 4)
                ? Bhi + (size_t)(bn + r) * Kp + k0 + q * 8
                : Blo + (size_t)(bn + r) * Kp + k0 + (q - 4) * 8;
            gload_lds16(src, &Bs[buf][0][0] + (size_t)(w * IB + i) * 512);
        }
    };

    f32x4 acc[FM][FN];
#pragma unroll
    for (int i = 0; i < FM; ++i)
#pragma unroll
        for (int j = 0; j < FN; ++j) acc[i][j] = (f32x4){0.f, 0.f, 0.f, 0.f};

    stage(0, 0);
    __syncthreads();

    for (int t = 0; t < nt; ++t) {
        int cur = t & 1, nxt = cur ^ 1;
        if (t + 1 < nt) stage((t + 1) * 32, nxt);

        bf16x8 ah[FM], al[FM], bh[FN], bl[FN];
#pragma unroll
        for (int fm = 0; fm < FM; ++fm) {
            const short* base = &As[cur][wrow + fm * 16 + lx][0];
            ah[fm] = *(const bf16x8*)(base + ((lg ^ l7) << 3));
            al[fm] = *(const bf16x8*)(base + (((lg + 4) ^ l7) << 3));
        }
#pragma unroll
        for (int fn = 0; fn < FN; ++fn) {
            const short* base = &Bs[cur][wcol + fn * 16 + lx][0];
            bh[fn] = *(const bf16x8*)(base + ((lg ^ l7) << 3));
            bl[fn] = *(const bf16x8*)(base + (((lg + 4) ^ l7) << 3));
        }
#pragma unroll
        for (int fm = 0; fm < FM; ++fm)
#pragma unroll
            for (int fn = 0; fn < FN; ++fn) {
                acc[fm][fn] = __builtin_amdgcn_mfma_f32_16x16x32_bf16(
                    ah[fm], bh[fn], acc[fm][fn], 0, 0, 0);
                acc[fm][fn] = __builtin_amdgcn_mfma_f32_16x16x32_bf16(
                    ah[fm], bl[fn], acc[fm][fn], 0, 0, 0);
                acc[fm][fn] = __builtin_amdgcn_mfma_f32_16x16x32_bf16(
                    al[fm], bh[fn], acc[fm][fn], 0, 0, 0);
            }
        __syncthreads();
    }

    // ---- epilogue: bias, relu, write f32 or split-bf16 ----
#pragma unroll
    for (int fm = 0; fm < FM; ++fm)
#pragma unroll
        for (int fn = 0; fn < FN; ++fn) {
            int colg = bn + wcol + fn * 16 + lx;
            float bb = (colg < Nb) ? bias[colg] : 0.f;
#pragma unroll
            for (int r = 0; r < 4; ++r) {
                int rowg = bm + wrow + fm * 16 + lg * 4 + r;
                float v = acc[fm][fn][r] + bb;
                if (RELU) v = fmaxf(v, 0.f);
                if constexpr (SPLIT) {
                    u16 h = f2bf(v);
                    size_t o = (size_t)rowg * N + colg;
                    Chi[o] = h;
                    Clo[o] = f2bf(v - bf2f(h));
                } else {
                    Cf[(size_t)rowg * N + colg] = v;
                }
            }
        }
}

// ---------------------------------------------------------------------------
// Transpose + split-bf16 convert:  W[K,N] f32  ->  BT{hi,lo}[Np][Kp] bf16
// Zero-fills padding in both dims. Grid (Kp/64, Np/64), 256 threads.
// ---------------------------------------------------------------------------
__global__ __launch_bounds__(256) void convtr_kernel(
    const float* __restrict__ W, u16* __restrict__ BThi, u16* __restrict__ BTlo,
    int K, int N, int Kp, int Np)
{
    __shared__ float T[64][65];
    int k0 = blockIdx.x * 64, n0 = blockIdx.y * 64;
    int c  = threadIdx.x & 63, r4 = threadIdx.x >> 6;
#pragma unroll
    for (int i = 0; i < 16; ++i) {
        int r = r4 * 16 + i;
        float v = 0.f;
        if (k0 + r < K && n0 + c < N) v = W[(size_t)(k0 + r) * N + n0 + c];
        T[r][c] = v;
    }
    __syncthreads();
#pragma unroll
    for (int i = 0; i < 16; ++i) {
        int nr = r4 * 16 + i;
        float v = T[c][nr];                      // = W[k0+c][n0+nr]
        u16 h = f2bf(v);
        size_t o = (size_t)(n0 + nr) * Kp + k0 + c;
        BThi[o] = h;
        BTlo[o] = f2bf(v - bf2f(h));
    }
}

// ---------------------------------------------------------------------------
// Row-wise split-bf16 convert with K padding: X[B,K] f32 -> {hi,lo}[B,Kp]
// ---------------------------------------------------------------------------
__global__ __launch_bounds__(256) void convpad_kernel(
    const float* __restrict__ X, u16* __restrict__ Hi, u16* __restrict__ Lo,
    int K, int Kp)
{
    int b = blockIdx.x;
    for (int k = threadIdx.x; k < Kp; k += 256) {
        float v = (k < K) ? X[(size_t)b * K + k] : 0.f;
        u16 h = f2bf(v);
        Hi[(size_t)b * Kp + k] = h;
        Lo[(size_t)b * Kp + k] = f2bf(v - bf2f(h));
    }
}

// ---------------------------------------------------------------------------
// theta_prep: unit-modulus theta -> thU; F1/F2 normalization -> out[200:264]
// (th1 rows have stride TH1_LD)
// ---------------------------------------------------------------------------
__global__ __launch_bounds__(128) void theta_prep_kernel(
    const float* __restrict__ th1, float* __restrict__ thU,
    float* __restrict__ out)
{
    int b   = blockIdx.x;
    int tid = threadIdx.x;
    const float* row = th1 + (size_t)b * TH1_LD;
    __shared__ float sc[2];

    if (tid == 112) {
        float s = 0.f;
        for (int j = 0; j < MN; ++j) {
            float fr = row[200 + j], fi = row[200 + MN + j];
            s += fr * fr + fi * fi;
        }
        sc[0] = sqrtf(2.f / s);
    } else if (tid == 113) {
        float s = 0.f;
        for (int j = 0; j < MN; ++j) {
            float fr = row[200 + 2 * MN + j], fi = row[200 + 3 * MN + j];
            s += fr * fr + fi * fi;
        }
        sc[1] = sqrtf(2.f / s);
    }

    if (tid < NRIS) {
        float re = row[tid], im = row[NRIS + tid];
        float r  = sqrtf(re * re + im * im);
        thU[(size_t)b * 200 + tid]        = re / r;
        thU[(size_t)b * 200 + NRIS + tid] = im / r;
    }
    __syncthreads();
    if (tid < 32) {
        int j = tid & 15, h = tid >> 4;
        out[(size_t)b * DOUT + 200 + h * MN + j]          = row[200 + h * MN + j] * sc[0];
        out[(size_t)b * DOUT + 200 + 2 * MN + h * MN + j] = row[200 + 2 * MN + h * MN + j] * sc[1];
    }
}

// ---------------------------------------------------------------------------
// quad+finalize fused: per b, compute CCC_c = Re(th^H T_c th)*1e15 for c=0..3,
// scale = rsqrt(max(max_c CCC, 1)), out[b][0:200] = thU*scale. 655 MB stream.
// ---------------------------------------------------------------------------
__global__ __launch_bounds__(256) void quadfin_kernel(
    const float* __restrict__ Tr, const float* __restrict__ Ti,
    const float* __restrict__ thU, float* __restrict__ out)
{
    int b   = blockIdx.x;
    int tid = threadIdx.x;

    __shared__ __align__(16) float sA[NRIS];
    __shared__ __align__(16) float sB[NRIS];
    if (tid < 200) {
        float v = thU[(size_t)b * 200 + tid];
        if (tid < NRIS) sA[tid] = v;
        else            sB[tid - NRIS] = v;
    }
    __syncthreads();

    float cc[4];
#pragma unroll
    for (int c = 0; c < 4; ++c) {
        const float4* R4 = (const float4*)(Tr + ((size_t)b * 4 + c) * (NRIS * NRIS));
        const float4* I4 = (const float4*)(Ti + ((size_t)b * 4 + c) * (NRIS * NRIS));
        float acc = 0.f;
        for (int j = tid; j < 2500; j += 256) {
            int n  = j / 25;
            int mb = (j - n * 25) * 4;
            float4 r  = R4[j];
            float4 im = I4[j];
            float an = sA[n], bn = sB[n];
            float4 am = *(const float4*)&sA[mb];
            float4 bm = *(const float4*)&sB[mb];
            acc += r.x * (an * am.x + bn * bm.x) + im.x * (bn * am.x - an * bm.x);
            acc += r.y * (an * am.y + bn * bm.y) + im.y * (bn * am.y - an * bm.y);
            acc += r.z * (an * am.z + bn * bm.z) + im.z * (bn * am.z - an * bm.z);
            acc += r.w * (an * am.w + bn * bm.w) + im.w * (bn * am.w - an * bm.w);
        }
        cc[c] = acc;
    }

    __shared__ float ws4[4][4];
    int wave = tid >> 6, lane = tid & 63;
#pragma unroll
    for (int c = 0; c < 4; ++c) {
        float a = cc[c];
        for (int off = 32; off > 0; off >>= 1) a += __shfl_down(a, off, 64);
        if (lane == 0) ws4[wave][c] = a;
    }
    __syncthreads();

    __shared__ float sc;
    if (tid == 0) {
        float mx = -1e30f;
#pragma unroll
        for (int c = 0; c < 4; ++c) {
            float s = ws4[0][c] + ws4[1][c] + ws4[2][c] + ws4[3][c];
            mx = fmaxf(mx, s);
        }
        mx *= 1e15f;
        sc = 1.f / sqrtf(fmaxf(mx, 1.0f));
    }
    __syncthreads();
    if (tid < NRIS) {
        out[(size_t)b * DOUT + tid]        = sA[tid] * sc;
        out[(size_t)b * DOUT + NRIS + tid] = sB[tid] * sc;
    }
}

// ---------------------------------------------------------------------------
// launch
// ---------------------------------------------------------------------------
extern "C" void kernel_launch(void* const* d_in, const int* in_sizes, int n_in,
                              void* d_out, int out_size, void* d_ws, size_t ws_size,
                              hipStream_t stream)
{
    const float* sample1 = (const float*)d_in[0];
    const float* T_real  = (const float*)d_in[1];
    const float* T_imag  = (const float*)d_in[2];
    const float* W1 = (const float*)d_in[3];
    const float* b1 = (const float*)d_in[4];
    const float* W2 = (const float*)d_in[5];
    const float* b2 = (const float*)d_in[6];
    const float* W3 = (const float*)d_in[7];
    const float* b3 = (const float*)d_in[8];
    const float* W4 = (const float*)d_in[9];
    const float* b4 = (const float*)d_in[10];
    float* out = (float*)d_out;

    // ---- workspace carve-up (bytes) ----
    char* p = (char*)d_ws;
    auto take = [&](size_t bytes) { char* q = p; p += bytes; return q; };
    u16* Shi   = (u16*)take((size_t)BATCH * 320 * 2);
    u16* Slo   = (u16*)take((size_t)BATCH * 320 * 2);
    u16* BT1hi = (u16*)take((size_t)1024 * 320 * 2);
    u16* BT1lo = (u16*)take((size_t)1024 * 320 * 2);
    u16* BT2hi = (u16*)take((size_t)1024 * 1024 * 2);
    u16* BT2lo = (u16*)take((size_t)1024 * 1024 * 2);
    u16* BT3hi = (u16*)take((size_t)512 * 1024 * 2);
    u16* BT3lo = (u16*)take((size_t)512 * 1024 * 2);
    u16* BT4hi = (u16*)take((size_t)320 * 512 * 2);
    u16* BT4lo = (u16*)take((size_t)320 * 512 * 2);
    u16* h1hi  = (u16*)take((size_t)BATCH * 1024 * 2);
    u16* h1lo  = (u16*)take((size_t)BATCH * 1024 * 2);
    u16* h2hi  = (u16*)take((size_t)BATCH * 1024 * 2);
    u16* h2lo  = (u16*)take((size_t)BATCH * 1024 * 2);
    u16* h3hi  = (u16*)take((size_t)BATCH * 512 * 2);
    u16* h3lo  = (u16*)take((size_t)BATCH * 512 * 2);
    float* th1 = (float*)take((size_t)BATCH * TH1_LD * 4);
    float* thU = (float*)take((size_t)BATCH * 200 * 4);

    dim3 blk(256);

    // ---- input conversions ----
    convpad_kernel<<<dim3(BATCH), blk, 0, stream>>>(sample1, Shi, Slo, DIN, 320);
    convtr_kernel<<<dim3(320 / 64, 1024 / 64), blk, 0, stream>>>(
        W1, BT1hi, BT1lo, DIN, 1024, 320, 1024);
    convtr_kernel<<<dim3(1024 / 64, 1024 / 64), blk, 0, stream>>>(
        W2, BT2hi, BT2lo, 1024, 1024, 1024, 1024);
    convtr_kernel<<<dim3(1024 / 64, 512 / 64), blk, 0, stream>>>(
        W3, BT3hi, BT3lo, 1024, 512, 1024, 512);
    convtr_kernel<<<dim3(512 / 64, 320 / 64), blk, 0, stream>>>(
        W4, BT4hi, BT4lo, 512, 264, 512, 320);

    // ---- MLP via split-bf16 MFMA ----
    // G1: 303->1024, Kp=320. grid (16,16)=256 blocks.
    gemm_bf16x3<128, 64, true, true><<<dim3(16, 16), blk, 0, stream>>>(
        Shi, Slo, BT1hi, BT1lo, b1, 1024, nullptr, h1hi, h1lo, BATCH, 1024, 320);
    // G2: 1024->1024. grid (16,16)=256 blocks.
    gemm_bf16x3<128, 64, true, true><<<dim3(16, 16), blk, 0, stream>>>(
        h1hi, h1lo, BT2hi, BT2lo, b2, 1024, nullptr, h2hi, h2lo, BATCH, 1024, 1024);
    // G3: 1024->512. grid (32,8)=256 blocks.
    gemm_bf16x3<64, 64, true, true><<<dim3(32, 8), blk, 0, stream>>>(
        h2hi, h2lo, BT3hi, BT3lo, b3, 512, nullptr, h3hi, h3lo, BATCH, 512, 1024);
    // G4: 512->264 (N padded to 320, bias guarded). grid (32,5)=160 blocks.
    gemm_bf16x3<64, 64, false, false><<<dim3(32, 5), blk, 0, stream>>>(
        h3hi, h3lo, BT4hi, BT4lo, b4, DOUT, th1, nullptr, nullptr, BATCH, TH1_LD, 512);

    // ---- theta path ----
    theta_prep_kernel<<<dim3(BATCH), dim3(128), 0, stream>>>(th1, thU, out);
    quadfin_kernel<<<dim3(BATCH), blk, 0, stream>>>(T_real, T_imag, thU, out);
}

// Round 3
// 739.746 us; speedup vs baseline: 1.1792x; 1.0273x over previous
//
#include <hip/hip_runtime.h>
#include <math.h>

// ---------------------------------------------------------------------------
// Problem constants
// ---------------------------------------------------------------------------
#define BATCH 2048
#define NRIS  100
#define MN    16
#define DIN   303
#define DOUT  264   // 200 + 4*16
#define TH1_LD 320  // padded row stride of th1 (N of GEMM4 padded to mult of 64)
// THRESH_W = 1e-15 -> CCC = quad * 1e15f

typedef short     bf16x8 __attribute__((ext_vector_type(8)));
typedef float     f32x4  __attribute__((ext_vector_type(4)));
typedef unsigned short u16;

// f32 -> bf16 (round-nearest-even), as raw u16
__device__ __forceinline__ u16 f2bf(float x) {
    unsigned u = __float_as_uint(x);
    unsigned r = (u + 0x7fffu + ((u >> 16) & 1u)) >> 16;
    return (u16)r;
}
__device__ __forceinline__ float bf2f(u16 h) {
    return __uint_as_float(((unsigned)h) << 16);
}

// async 16B global->LDS DMA (wave-uniform LDS base + lane*16 semantics)
__device__ __forceinline__ void gload_lds16(const void* g, void* lds) {
    __builtin_amdgcn_global_load_lds(
        (const __attribute__((address_space(1))) unsigned int*)g,
        (__attribute__((address_space(3))) unsigned int*)lds, 16, 0, 0);
}

// ---------------------------------------------------------------------------
// Split-bf16 MFMA GEMM:  C[M,N] = act(A @ B + bias)
//   A given as (Ahi,Alo)  [M,Kp] bf16 row-major
//   B given as (Bhi,Blo)  [N,Kp] bf16 row-major  (i.e. B^T, k-contiguous)
//   acc += ahi*bhi + ahi*blo + alo*bhi   (3x mfma_f32_16x16x32_bf16)
// 256 threads = 4 waves in 2x2; wave tile (BM/2)x(BN/2); frags 16x16.
// BM in {32,64,128}. Occupancy rationale (256 CUs): pick BM so the grid is
// >=320 blocks -> >=2 blocks/CU; the per-K-step vmcnt(0) drain at the barrier
// then overlaps with the co-resident block's compute (1 block/CU exposes the
// full global-load latency every K-step).
// LDS tile rows are [64 bf16] = 8 slots of 16B: slots 0-3 = hi k0..31,
// slots 4-7 = lo k0..31, XOR-swizzled: phys_slot = logical ^ (row&7).
// Staging via global_load_lds with pre-swizzled per-lane SOURCE address
// (linear LDS dest), reads apply the same XOR -> 2-way conflicts only.
// Fragment k-mapping: lane holds 8 contiguous k (k = (lane>>4)*8 + e) for
// BOTH operands -> contraction pairing correct for any HW-internal k-order.
// C/D layout (HW-verified): col = lane&15, row = (lane>>4)*4 + reg.
// Requires M%BM==0, N%BN==0, Kp%32==0.
// ---------------------------------------------------------------------------
template <int BM, int BN, bool RELU, bool SPLIT>
__global__ __launch_bounds__(256) void gemm_bf16x3(
    const u16* __restrict__ Ahi, const u16* __restrict__ Alo,
    const u16* __restrict__ Bhi, const u16* __restrict__ Blo,
    const float* __restrict__ bias, int Nb,
    float* __restrict__ Cf, u16* __restrict__ Chi, u16* __restrict__ Clo,
    int M, int N, int Kp)
{
    constexpr int WR = BM / 2, WC = BN / 2;    // per-wave tile
    constexpr int FM = WR / 16, FN = WC / 16;  // 16x16 frags per wave
    constexpr int IA = BM / 32;                // gload insts/wave for A tile
    constexpr int IB = BN / 32;

    __shared__ __align__(16) short As[2][BM][64];
    __shared__ __align__(16) short Bs[2][BN][64];

    const int tid = threadIdx.x;
    const int w  = tid >> 6, l = tid & 63;
    const int lg = l >> 4, lx = l & 15, l7 = l & 7;
    const int bm = blockIdx.x * BM, bn = blockIdx.y * BN;
    const int wrow = (w >> 1) * WR, wcol = (w & 1) * WC;
    const int nt = Kp / 32;

    auto stage = [&](int k0, int buf) {
#pragma unroll
        for (int i = 0; i < IA; ++i) {
            int fi = (w * IA + i) * 64 + l;          // f4-slot index in tile
            int r = fi >> 3, p = fi & 7, q = p ^ (r & 7);
            const u16* src = (q < 4)
                ? Ahi + (size_t)(bm + r) * Kp + k0 + q * 8
                : Alo + (size_t)(bm + r) * Kp + k0 + (q - 4) * 8;
            gload_lds16(src, &As[buf][0][0] + (size_t)(w * IA + i) * 512);
        }
#pragma unroll
        for (int i = 0; i < IB; ++i) {
            int fi = (w * IB + i) * 64 + l;
            int r = fi >> 3, p = fi & 7, q = p ^ (r & 7);
            const u16* src = (q < 4)
                ? Bhi + (size_t)(bn + r) * Kp + k0 + q * 8
                : Blo + (size_t)(bn + r) * Kp + k0 + (q - 4) * 8;
            gload_lds16(src, &Bs[buf][0][0] + (size_t)(w * IB + i) * 512);
        }
    };

    f32x4 acc[FM][FN];
#pragma unroll
    for (int i = 0; i < FM; ++i)
#pragma unroll
        for (int j = 0; j < FN; ++j) acc[i][j] = (f32x4){0.f, 0.f, 0.f, 0.f};

    stage(0, 0);
    __syncthreads();

    for (int t = 0; t < nt; ++t) {
        int cur = t & 1, nxt = cur ^ 1;
        if (t + 1 < nt) stage((t + 1) * 32, nxt);

        bf16x8 ah[FM], al[FM], bh[FN], bl[FN];
#pragma unroll
        for (int fm = 0; fm < FM; ++fm) {
            const short* base = &As[cur][wrow + fm * 16 + lx][0];
            ah[fm] = *(const bf16x8*)(base + ((lg ^ l7) << 3));
            al[fm] = *(const bf16x8*)(base + (((lg + 4) ^ l7) << 3));
        }
#pragma unroll
        for (int fn = 0; fn < FN; ++fn) {
            const short* base = &Bs[cur][wcol + fn * 16 + lx][0];
            bh[fn] = *(const bf16x8*)(base + ((lg ^ l7) << 3));
            bl[fn] = *(const bf16x8*)(base + (((lg + 4) ^ l7) << 3));
        }
#pragma unroll
        for (int fm = 0; fm < FM; ++fm)
#pragma unroll
            for (int fn = 0; fn < FN; ++fn) {
                acc[fm][fn] = __builtin_amdgcn_mfma_f32_16x16x32_bf16(
                    ah[fm], bh[fn], acc[fm][fn], 0, 0, 0);
                acc[fm][fn] = __builtin_amdgcn_mfma_f32_16x16x32_bf16(
                    ah[fm], bl[fn], acc[fm][fn], 0, 0, 0);
                acc[fm][fn] = __builtin_amdgcn_mfma_f32_16x16x32_bf16(
                    al[fm], bh[fn], acc[fm][fn], 0, 0, 0);
            }
        __syncthreads();
    }

    // ---- epilogue: bias, relu, write f32 or split-bf16 ----
#pragma unroll
    for (int fm = 0; fm < FM; ++fm)
#pragma unroll
        for (int fn = 0; fn < FN; ++fn) {
            int colg = bn + wcol + fn * 16 + lx;
            float bb = (colg < Nb) ? bias[colg] : 0.f;
#pragma unroll
            for (int r = 0; r < 4; ++r) {
                int rowg = bm + wrow + fm * 16 + lg * 4 + r;
                float v = acc[fm][fn][r] + bb;
                if (RELU) v = fmaxf(v, 0.f);
                if constexpr (SPLIT) {
                    u16 h = f2bf(v);
                    size_t o = (size_t)rowg * N + colg;
                    Chi[o] = h;
                    Clo[o] = f2bf(v - bf2f(h));
                } else {
                    Cf[(size_t)rowg * N + colg] = v;
                }
            }
        }
}

// ---------------------------------------------------------------------------
// Transpose + split-bf16 convert:  W[K,N] f32  ->  BT{hi,lo}[Np][Kp] bf16
// Zero-fills padding in both dims. Grid (Kp/64, Np/64), 256 threads.
// ---------------------------------------------------------------------------
__global__ __launch_bounds__(256) void convtr_kernel(
    const float* __restrict__ W, u16* __restrict__ BThi, u16* __restrict__ BTlo,
    int K, int N, int Kp, int Np)
{
    __shared__ float T[64][65];
    int k0 = blockIdx.x * 64, n0 = blockIdx.y * 64;
    int c  = threadIdx.x & 63, r4 = threadIdx.x >> 6;
#pragma unroll
    for (int i = 0; i < 16; ++i) {
        int r = r4 * 16 + i;
        float v = 0.f;
        if (k0 + r < K && n0 + c < N) v = W[(size_t)(k0 + r) * N + n0 + c];
        T[r][c] = v;
    }
    __syncthreads();
#pragma unroll
    for (int i = 0; i < 16; ++i) {
        int nr = r4 * 16 + i;
        float v = T[c][nr];                      // = W[k0+c][n0+nr]
        u16 h = f2bf(v);
        size_t o = (size_t)(n0 + nr) * Kp + k0 + c;
        BThi[o] = h;
        BTlo[o] = f2bf(v - bf2f(h));
    }
}

// ---------------------------------------------------------------------------
// Row-wise split-bf16 convert with K padding: X[B,K] f32 -> {hi,lo}[B,Kp]
// ---------------------------------------------------------------------------
__global__ __launch_bounds__(256) void convpad_kernel(
    const float* __restrict__ X, u16* __restrict__ Hi, u16* __restrict__ Lo,
    int K, int Kp)
{
    int b = blockIdx.x;
    for (int k = threadIdx.x; k < Kp; k += 256) {
        float v = (k < K) ? X[(size_t)b * K + k] : 0.f;
        u16 h = f2bf(v);
        Hi[(size_t)b * Kp + k] = h;
        Lo[(size_t)b * Kp + k] = f2bf(v - bf2f(h));
    }
}

// ---------------------------------------------------------------------------
// theta_prep: unit-modulus theta -> thU; F1/F2 normalization -> out[200:264]
// (th1 rows have stride TH1_LD)
// ---------------------------------------------------------------------------
__global__ __launch_bounds__(128) void theta_prep_kernel(
    const float* __restrict__ th1, float* __restrict__ thU,
    float* __restrict__ out)
{
    int b   = blockIdx.x;
    int tid = threadIdx.x;
    const float* row = th1 + (size_t)b * TH1_LD;
    __shared__ float sc[2];

    if (tid == 112) {
        float s = 0.f;
        for (int j = 0; j < MN; ++j) {
            float fr = row[200 + j], fi = row[200 + MN + j];
            s += fr * fr + fi * fi;
        }
        sc[0] = sqrtf(2.f / s);
    } else if (tid == 113) {
        float s = 0.f;
        for (int j = 0; j < MN; ++j) {
            float fr = row[200 + 2 * MN + j], fi = row[200 + 3 * MN + j];
            s += fr * fr + fi * fi;
        }
        sc[1] = sqrtf(2.f / s);
    }

    if (tid < NRIS) {
        float re = row[tid], im = row[NRIS + tid];
        float r  = sqrtf(re * re + im * im);
        thU[(size_t)b * 200 + tid]        = re / r;
        thU[(size_t)b * 200 + NRIS + tid] = im / r;
    }
    __syncthreads();
    if (tid < 32) {
        int j = tid & 15, h = tid >> 4;
        out[(size_t)b * DOUT + 200 + h * MN + j]          = row[200 + h * MN + j] * sc[0];
        out[(size_t)b * DOUT + 200 + 2 * MN + h * MN + j] = row[200 + 2 * MN + h * MN + j] * sc[1];
    }
}

// ---------------------------------------------------------------------------
// quad+finalize fused: per b, CCC_c = Re(th^H T_c th)*1e15 for c=0..3,
// scale = rsqrt(max(max_c CCC, 1)), out[b][0:200] = thU*scale.
// 655 MB stream -> HBM-bound; all 4 constraint streams interleaved per j
// (8 outstanding 16B loads/lane), shared tR/tI hoisted out of the c-loop,
// incremental (n,m) indexing (no int div in loop): 256 = 10*25 + 6.
// ---------------------------------------------------------------------------
__global__ __launch_bounds__(256) void quadfin_kernel(
    const float* __restrict__ Tr, const float* __restrict__ Ti,
    const float* __restrict__ thU, float* __restrict__ out)
{
    int b   = blockIdx.x;
    int tid = threadIdx.x;

    __shared__ __align__(16) float sA[NRIS];
    __shared__ __align__(16) float sB[NRIS];
    if (tid < 200) {
        float v = thU[(size_t)b * 200 + tid];
        if (tid < NRIS) sA[tid] = v;
        else            sB[tid - NRIS] = v;
    }
    __syncthreads();

    const float4* R0 = (const float4*)(Tr + (size_t)b * 4 * (NRIS * NRIS));
    const float4* I0 = (const float4*)(Ti + (size_t)b * 4 * (NRIS * NRIS));

    float acc0 = 0.f, acc1 = 0.f, acc2 = 0.f, acc3 = 0.f;
    int n = tid / 25;            // one div at entry only
    int m = tid - n * 25;
    for (int j = tid; j < 2500; j += 256) {
        float an = sA[n], bn = sB[n];
        float4 am = *(const float4*)&sA[m * 4];
        float4 bm = *(const float4*)&sB[m * 4];
        float4 tR, tI;
        tR.x = an * am.x + bn * bm.x;  tI.x = bn * am.x - an * bm.x;
        tR.y = an * am.y + bn * bm.y;  tI.y = bn * am.y - an * bm.y;
        tR.z = an * am.z + bn * bm.z;  tI.z = bn * am.z - an * bm.z;
        tR.w = an * am.w + bn * bm.w;  tI.w = bn * am.w - an * bm.w;

        float4 r0 = R0[j],            i0 = I0[j];
        float4 r1 = R0[2500 + j],     i1 = I0[2500 + j];
        float4 r2 = R0[5000 + j],     i2 = I0[5000 + j];
        float4 r3 = R0[7500 + j],     i3 = I0[7500 + j];

        acc0 += r0.x * tR.x + r0.y * tR.y + r0.z * tR.z + r0.w * tR.w
              + i0.x * tI.x + i0.y * tI.y + i0.z * tI.z + i0.w * tI.w;
        acc1 += r1.x * tR.x + r1.y * tR.y + r1.z * tR.z + r1.w * tR.w
              + i1.x * tI.x + i1.y * tI.y + i1.z * tI.z + i1.w * tI.w;
        acc2 += r2.x * tR.x + r2.y * tR.y + r2.z * tR.z + r2.w * tR.w
              + i2.x * tI.x + i2.y * tI.y + i2.z * tI.z + i2.w * tI.w;
        acc3 += r3.x * tR.x + r3.y * tR.y + r3.z * tR.z + r3.w * tR.w
              + i3.x * tI.x + i3.y * tI.y + i3.z * tI.z + i3.w * tI.w;

        n += 10; m += 6;
        if (m >= 25) { m -= 25; ++n; }
    }

    int wave = tid >> 6, lane = tid & 63;
    for (int off = 32; off > 0; off >>= 1) {
        acc0 += __shfl_down(acc0, off, 64);
        acc1 += __shfl_down(acc1, off, 64);
        acc2 += __shfl_down(acc2, off, 64);
        acc3 += __shfl_down(acc3, off, 64);
    }
    __shared__ float ws4[4][4];
    if (lane == 0) {
        ws4[wave][0] = acc0; ws4[wave][1] = acc1;
        ws4[wave][2] = acc2; ws4[wave][3] = acc3;
    }
    __syncthreads();

    __shared__ float sc;
    if (tid == 0) {
        float mx = -1e30f;
#pragma unroll
        for (int c = 0; c < 4; ++c) {
            float s = ws4[0][c] + ws4[1][c] + ws4[2][c] + ws4[3][c];
            mx = fmaxf(mx, s);
        }
        mx *= 1e15f;
        sc = 1.f / sqrtf(fmaxf(mx, 1.0f));
    }
    __syncthreads();
    if (tid < NRIS) {
        out[(size_t)b * DOUT + tid]        = sA[tid] * sc;
        out[(size_t)b * DOUT + NRIS + tid] = sB[tid] * sc;
    }
}

// ---------------------------------------------------------------------------
// launch
// ---------------------------------------------------------------------------
extern "C" void kernel_launch(void* const* d_in, const int* in_sizes, int n_in,
                              void* d_out, int out_size, void* d_ws, size_t ws_size,
                              hipStream_t stream)
{
    const float* sample1 = (const float*)d_in[0];
    const float* T_real  = (const float*)d_in[1];
    const float* T_imag  = (const float*)d_in[2];
    const float* W1 = (const float*)d_in[3];
    const float* b1 = (const float*)d_in[4];
    const float* W2 = (const float*)d_in[5];
    const float* b2 = (const float*)d_in[6];
    const float* W3 = (const float*)d_in[7];
    const float* b3 = (const float*)d_in[8];
    const float* W4 = (const float*)d_in[9];
    const float* b4 = (const float*)d_in[10];
    float* out = (float*)d_out;

    // ---- workspace carve-up (bytes) ----
    char* p = (char*)d_ws;
    auto take = [&](size_t bytes) { char* q = p; p += bytes; return q; };
    u16* Shi   = (u16*)take((size_t)BATCH * 320 * 2);
    u16* Slo   = (u16*)take((size_t)BATCH * 320 * 2);
    u16* BT1hi = (u16*)take((size_t)1024 * 320 * 2);
    u16* BT1lo = (u16*)take((size_t)1024 * 320 * 2);
    u16* BT2hi = (u16*)take((size_t)1024 * 1024 * 2);
    u16* BT2lo = (u16*)take((size_t)1024 * 1024 * 2);
    u16* BT3hi = (u16*)take((size_t)512 * 1024 * 2);
    u16* BT3lo = (u16*)take((size_t)512 * 1024 * 2);
    u16* BT4hi = (u16*)take((size_t)320 * 512 * 2);
    u16* BT4lo = (u16*)take((size_t)320 * 512 * 2);
    u16* h1hi  = (u16*)take((size_t)BATCH * 1024 * 2);
    u16* h1lo  = (u16*)take((size_t)BATCH * 1024 * 2);
    u16* h2hi  = (u16*)take((size_t)BATCH * 1024 * 2);
    u16* h2lo  = (u16*)take((size_t)BATCH * 1024 * 2);
    u16* h3hi  = (u16*)take((size_t)BATCH * 512 * 2);
    u16* h3lo  = (u16*)take((size_t)BATCH * 512 * 2);
    float* th1 = (float*)take((size_t)BATCH * TH1_LD * 4);
    float* thU = (float*)take((size_t)BATCH * 200 * 4);

    dim3 blk(256);

    // ---- input conversions ----
    convpad_kernel<<<dim3(BATCH), blk, 0, stream>>>(sample1, Shi, Slo, DIN, 320);
    convtr_kernel<<<dim3(320 / 64, 1024 / 64), blk, 0, stream>>>(
        W1, BT1hi, BT1lo, DIN, 1024, 320, 1024);
    convtr_kernel<<<dim3(1024 / 64, 1024 / 64), blk, 0, stream>>>(
        W2, BT2hi, BT2lo, 1024, 1024, 1024, 1024);
    convtr_kernel<<<dim3(1024 / 64, 512 / 64), blk, 0, stream>>>(
        W3, BT3hi, BT3lo, 1024, 512, 1024, 512);
    convtr_kernel<<<dim3(512 / 64, 320 / 64), blk, 0, stream>>>(
        W4, BT4hi, BT4lo, 512, 264, 512, 320);

    // ---- MLP via split-bf16 MFMA (all grids >= 320 blocks -> 2 blocks/CU) ----
    // G1: 303->1024, Kp=320. grid (32,16)=512.
    gemm_bf16x3<64, 64, true, true><<<dim3(32, 16), blk, 0, stream>>>(
        Shi, Slo, BT1hi, BT1lo, b1, 1024, nullptr, h1hi, h1lo, BATCH, 1024, 320);
    // G2: 1024->1024. grid (32,16)=512.
    gemm_bf16x3<64, 64, true, true><<<dim3(32, 16), blk, 0, stream>>>(
        h1hi, h1lo, BT2hi, BT2lo, b2, 1024, nullptr, h2hi, h2lo, BATCH, 1024, 1024);
    // G3: 1024->512. grid (64,8)=512.
    gemm_bf16x3<32, 64, true, true><<<dim3(64, 8), blk, 0, stream>>>(
        h2hi, h2lo, BT3hi, BT3lo, b3, 512, nullptr, h3hi, h3lo, BATCH, 512, 1024);
    // G4: 512->264 (N padded to 320, bias guarded). grid (64,5)=320.
    gemm_bf16x3<32, 64, false, false><<<dim3(64, 5), blk, 0, stream>>>(
        h3hi, h3lo, BT4hi, BT4lo, b4, DOUT, th1, nullptr, nullptr, BATCH, TH1_LD, 512);

    // ---- theta path ----
    theta_prep_kernel<<<dim3(BATCH), dim3(128), 0, stream>>>(th1, thU, out);
    quadfin_kernel<<<dim3(BATCH), blk, 0, stream>>>(T_real, T_imag, thU, out);
}

// Round 4
// 692.975 us; speedup vs baseline: 1.2587x; 1.0675x over previous
//
#include <hip/hip_runtime.h>
#include <math.h>

// ---------------------------------------------------------------------------
// Problem constants
// ---------------------------------------------------------------------------
#define BATCH 2048
#define NRIS  100
#define MN    16
#define DIN   303
#define DOUT  264   // 200 + 4*16
#define TH1_LD 320  // padded row stride of th1 (N of GEMM4 padded to mult of 64)
// THRESH_W = 1e-15 -> CCC = quad * 1e15f

typedef short     bf16x8 __attribute__((ext_vector_type(8)));
typedef float     f32x4  __attribute__((ext_vector_type(4)));
typedef unsigned short u16;

// f32 -> bf16 (round-nearest-even), as raw u16
__device__ __forceinline__ u16 f2bf(float x) {
    unsigned u = __float_as_uint(x);
    unsigned r = (u + 0x7fffu + ((u >> 16) & 1u)) >> 16;
    return (u16)r;
}
__device__ __forceinline__ float bf2f(u16 h) {
    return __uint_as_float(((unsigned)h) << 16);
}

// async 16B global->LDS DMA (wave-uniform LDS base + lane*16 semantics)
__device__ __forceinline__ void gload_lds16(const void* g, void* lds) {
    __builtin_amdgcn_global_load_lds(
        (const __attribute__((address_space(1))) unsigned int*)g,
        (__attribute__((address_space(3))) unsigned int*)lds, 16, 0, 0);
}

// ---------------------------------------------------------------------------
// Split-bf16 MFMA GEMM, BK=64:  C[M,N] = act(A @ B + bias)
//   A given as (Ahi,Alo)  [M,Kp] bf16 row-major
//   B given as (Bhi,Blo)  [N,Kp] bf16 row-major  (i.e. B^T, k-contiguous)
//   acc += ahi*bhi + ahi*blo + alo*bhi   (3x mfma_f32_16x16x32_bf16)
// 256 threads = 4 waves in 2x2; wave tile (BM/2)x(BN/2); frags 16x16.
// BK=64 rationale: the per-iteration __syncthreads drains the just-issued
// next-tile DMAs (vmcnt(0), ~300-500cy). BK=64 halves the drain count and
// doubles MFMA per drain (24/wave/iter) vs the BK=32 version.
// LDS rows = [128 bf16] = 16 slots of 16B: slots 0-7 = hi k0..63,
// slots 8-15 = lo k0..63, XOR-swizzled: phys_slot = logical ^ (row&15)
// (rule 21: applied identically on DMA *source* address and ds_read).
// Fragment k-mapping: lane holds 8 contiguous k (k = (lane>>4)*8 + e) for
// BOTH operands -> contraction pairing correct for any HW-internal k-order.
// C/D layout (HW-verified): col = lane&15, row = (lane>>4)*4 + reg.
// Requires M%BM==0, N%BN==0, Kp%64==0.
// ---------------------------------------------------------------------------
template <int BM, int BN, bool RELU, bool SPLIT>
__global__ __launch_bounds__(256) void gemm_bf16x3(
    const u16* __restrict__ Ahi, const u16* __restrict__ Alo,
    const u16* __restrict__ Bhi, const u16* __restrict__ Blo,
    const float* __restrict__ bias, int Nb,
    float* __restrict__ Cf, u16* __restrict__ Chi, u16* __restrict__ Clo,
    int M, int N, int Kp)
{
    constexpr int WR = BM / 2, WC = BN / 2;    // per-wave tile
    constexpr int FM = WR / 16, FN = WC / 16;  // 16x16 frags per wave
    constexpr int IA = BM / 16;                // DMA insts/wave for A tile
    constexpr int IB = BN / 16;

    __shared__ __align__(16) short As[2][BM][128];
    __shared__ __align__(16) short Bs[2][BN][128];

    const int tid = threadIdx.x;
    const int w  = tid >> 6, l = tid & 63;
    const int lg = l >> 4, lx = l & 15;
    const int bm = blockIdx.x * BM, bn = blockIdx.y * BN;
    const int wrow = (w >> 1) * WR, wcol = (w & 1) * WC;
    const int nt = Kp / 64;

    auto stage = [&](int k0, int buf) {
#pragma unroll
        for (int i = 0; i < IA; ++i) {
            int fi = (w * IA + i) * 64 + l;          // 16B-slot index in tile
            int r = fi >> 4, p = fi & 15, q = p ^ (r & 15);
            const u16* src = (q < 8)
                ? Ahi + (size_t)(bm + r) * Kp + k0 + q * 8
                : Alo + (size_t)(bm + r) * Kp + k0 + (q - 8) * 8;
            gload_lds16(src, &As[buf][0][0] + (size_t)(w * IA + i) * 512);
        }
#pragma unroll
        for (int i = 0; i < IB; ++i) {
            int fi = (w * IB + i) * 64 + l;
            int r = fi >> 4, p = fi & 15, q = p ^ (r & 15);
            const u16* src = (q < 8)
                ? Bhi + (size_t)(bn + r) * Kp + k0 + q * 8
                : Blo + (size_t)(bn + r) * Kp + k0 + (q - 8) * 8;
            gload_lds16(src, &Bs[buf][0][0] + (size_t)(w * IB + i) * 512);
        }
    };

    f32x4 acc[FM][FN];
#pragma unroll
    for (int i = 0; i < FM; ++i)
#pragma unroll
        for (int j = 0; j < FN; ++j) acc[i][j] = (f32x4){0.f, 0.f, 0.f, 0.f};

    stage(0, 0);
    __syncthreads();

    for (int t = 0; t < nt; ++t) {
        int cur = t & 1, nxt = cur ^ 1;
        if (t + 1 < nt) stage((t + 1) * 64, nxt);

#pragma unroll
        for (int s = 0; s < 2; ++s) {      // two K=32 halves of the K=64 tile
            bf16x8 ah[FM], al[FM], bh[FN], bl[FN];
#pragma unroll
            for (int fm = 0; fm < FM; ++fm) {
                int row = wrow + fm * 16 + lx;
                const short* base = &As[cur][row][0];
                int r15 = row & 15;
                ah[fm] = *(const bf16x8*)(base + (((s * 4 + lg) ^ r15) << 3));
                al[fm] = *(const bf16x8*)(base + (((8 + s * 4 + lg) ^ r15) << 3));
            }
#pragma unroll
            for (int fn = 0; fn < FN; ++fn) {
                int row = wcol + fn * 16 + lx;
                const short* base = &Bs[cur][row][0];
                int r15 = row & 15;
                bh[fn] = *(const bf16x8*)(base + (((s * 4 + lg) ^ r15) << 3));
                bl[fn] = *(const bf16x8*)(base + (((8 + s * 4 + lg) ^ r15) << 3));
            }
#pragma unroll
            for (int fm = 0; fm < FM; ++fm)
#pragma unroll
                for (int fn = 0; fn < FN; ++fn) {
                    acc[fm][fn] = __builtin_amdgcn_mfma_f32_16x16x32_bf16(
                        ah[fm], bh[fn], acc[fm][fn], 0, 0, 0);
                    acc[fm][fn] = __builtin_amdgcn_mfma_f32_16x16x32_bf16(
                        ah[fm], bl[fn], acc[fm][fn], 0, 0, 0);
                    acc[fm][fn] = __builtin_amdgcn_mfma_f32_16x16x32_bf16(
                        al[fm], bh[fn], acc[fm][fn], 0, 0, 0);
                }
        }
        __syncthreads();
    }

    // ---- epilogue: bias, relu, write f32 or split-bf16 ----
#pragma unroll
    for (int fm = 0; fm < FM; ++fm)
#pragma unroll
        for (int fn = 0; fn < FN; ++fn) {
            int colg = bn + wcol + fn * 16 + lx;
            float bb = (colg < Nb) ? bias[colg] : 0.f;
#pragma unroll
            for (int r = 0; r < 4; ++r) {
                int rowg = bm + wrow + fm * 16 + lg * 4 + r;
                float v = acc[fm][fn][r] + bb;
                if (RELU) v = fmaxf(v, 0.f);
                if constexpr (SPLIT) {
                    u16 h = f2bf(v);
                    size_t o = (size_t)rowg * N + colg;
                    Chi[o] = h;
                    Clo[o] = f2bf(v - bf2f(h));
                } else {
                    Cf[(size_t)rowg * N + colg] = v;
                }
            }
        }
}

// ---------------------------------------------------------------------------
// Fused conversion kernel (one launch replaces 5):
//  blocks [0,504):   transpose+split of W1..W4 -> BT{hi,lo}[Np][Kp]
//  blocks [504,2552): row-wise pad+split of sample1 -> S{hi,lo}[B][320]
// ---------------------------------------------------------------------------
__global__ __launch_bounds__(256) void convert_all_kernel(
    const float* __restrict__ s1,
    const float* __restrict__ W1, const float* __restrict__ W2,
    const float* __restrict__ W3, const float* __restrict__ W4,
    u16* __restrict__ Shi, u16* __restrict__ Slo,
    u16* __restrict__ B1h, u16* __restrict__ B1l,
    u16* __restrict__ B2h, u16* __restrict__ B2l,
    u16* __restrict__ B3h, u16* __restrict__ B3l,
    u16* __restrict__ B4h, u16* __restrict__ B4l)
{
    int bid = blockIdx.x;
    if (bid >= 504) {
        int b = bid - 504;
        for (int k = threadIdx.x; k < 320; k += 256) {
            float v = (k < DIN) ? s1[(size_t)b * DIN + k] : 0.f;
            u16 h = f2bf(v);
            Shi[(size_t)b * 320 + k] = h;
            Slo[(size_t)b * 320 + k] = f2bf(v - bf2f(h));
        }
        return;
    }
    const float* W; u16 *Hh, *Ll; int K, N, Kp, gw;
    if (bid < 80)       {            W = W1; Hh = B1h; Ll = B1l; K = DIN;  N = 1024; Kp = 320;  gw = 5;  }
    else if (bid < 336) { bid -= 80;  W = W2; Hh = B2h; Ll = B2l; K = 1024; N = 1024; Kp = 1024; gw = 16; }
    else if (bid < 464) { bid -= 336; W = W3; Hh = B3h; Ll = B3l; K = 1024; N = 512;  Kp = 1024; gw = 16; }
    else                { bid -= 464; W = W4; Hh = B4h; Ll = B4l; K = 512;  N = DOUT; Kp = 512;  gw = 8;  }

    __shared__ float T[64][65];
    int k0 = (bid % gw) * 64, n0 = (bid / gw) * 64;
    int c  = threadIdx.x & 63, r4 = threadIdx.x >> 6;
#pragma unroll
    for (int i = 0; i < 16; ++i) {
        int r = r4 * 16 + i;
        float v = 0.f;
        if (k0 + r < K && n0 + c < N) v = W[(size_t)(k0 + r) * N + n0 + c];
        T[r][c] = v;
    }
    __syncthreads();
#pragma unroll
    for (int i = 0; i < 16; ++i) {
        int nr = r4 * 16 + i;
        float v = T[c][nr];                      // = W[k0+c][n0+nr]
        u16 h = f2bf(v);
        size_t o = (size_t)(n0 + nr) * Kp + k0 + c;
        Hh[o] = h;
        Ll[o] = f2bf(v - bf2f(h));
    }
}

// ---------------------------------------------------------------------------
// quad+finalize+theta_prep fused: per b,
//   theta = th1[0:100]+i*th1[100:200]; theta /= |theta|  (into LDS sA,sB)
//   F1/F2 norm -> out[200:264]
//   CCC_c = Re(th^H T_c th)*1e15, scale = rsqrt(max(max_c CCC,1))
//   out[0:200] = theta * scale
// 655 MB T stream -> HBM-bound; 4 constraint streams interleaved per j
// (8 outstanding 16B loads/lane), incremental (n,m) (no div in loop).
// ---------------------------------------------------------------------------
__global__ __launch_bounds__(256) void quadfin_kernel(
    const float* __restrict__ Tr, const float* __restrict__ Ti,
    const float* __restrict__ th1, float* __restrict__ out)
{
    int b   = blockIdx.x;
    int tid = threadIdx.x;
    const float* row = th1 + (size_t)b * TH1_LD;

    __shared__ __align__(16) float sA[NRIS];
    __shared__ __align__(16) float sB[NRIS];
    __shared__ float sc2[2];

    if (tid < NRIS) {
        float re = row[tid], im = row[NRIS + tid];
        float rr = sqrtf(re * re + im * im);
        sA[tid] = re / rr;
        sB[tid] = im / rr;
    } else if (tid == 112) {
        float s = 0.f;
        for (int j = 0; j < MN; ++j) {
            float fr = row[200 + j], fi = row[200 + MN + j];
            s += fr * fr + fi * fi;
        }
        sc2[0] = sqrtf(2.f / s);
    } else if (tid == 113) {
        float s = 0.f;
        for (int j = 0; j < MN; ++j) {
            float fr = row[200 + 2 * MN + j], fi = row[200 + 3 * MN + j];
            s += fr * fr + fi * fi;
        }
        sc2[1] = sqrtf(2.f / s);
    }
    __syncthreads();
    if (tid < 32) {
        int j = tid & 15, h = tid >> 4;
        out[(size_t)b * DOUT + 200 + h * MN + j]          = row[200 + h * MN + j] * sc2[0];
        out[(size_t)b * DOUT + 200 + 2 * MN + h * MN + j] = row[200 + 2 * MN + h * MN + j] * sc2[1];
    }

    const float4* R0 = (const float4*)(Tr + (size_t)b * 4 * (NRIS * NRIS));
    const float4* I0 = (const float4*)(Ti + (size_t)b * 4 * (NRIS * NRIS));

    float acc0 = 0.f, acc1 = 0.f, acc2 = 0.f, acc3 = 0.f;
    int n = tid / 25;            // one div at entry only
    int m = tid - n * 25;
    for (int j = tid; j < 2500; j += 256) {
        float an = sA[n], bn = sB[n];
        float4 am = *(const float4*)&sA[m * 4];
        float4 bm = *(const float4*)&sB[m * 4];
        float4 tR, tI;
        tR.x = an * am.x + bn * bm.x;  tI.x = bn * am.x - an * bm.x;
        tR.y = an * am.y + bn * bm.y;  tI.y = bn * am.y - an * bm.y;
        tR.z = an * am.z + bn * bm.z;  tI.z = bn * am.z - an * bm.z;
        tR.w = an * am.w + bn * bm.w;  tI.w = bn * am.w - an * bm.w;

        float4 r0 = R0[j],            i0 = I0[j];
        float4 r1 = R0[2500 + j],     i1 = I0[2500 + j];
        float4 r2 = R0[5000 + j],     i2 = I0[5000 + j];
        float4 r3 = R0[7500 + j],     i3 = I0[7500 + j];

        acc0 += r0.x * tR.x + r0.y * tR.y + r0.z * tR.z + r0.w * tR.w
              + i0.x * tI.x + i0.y * tI.y + i0.z * tI.z + i0.w * tI.w;
        acc1 += r1.x * tR.x + r1.y * tR.y + r1.z * tR.z + r1.w * tR.w
              + i1.x * tI.x + i1.y * tI.y + i1.z * tI.z + i1.w * tI.w;
        acc2 += r2.x * tR.x + r2.y * tR.y + r2.z * tR.z + r2.w * tR.w
              + i2.x * tI.x + i2.y * tI.y + i2.z * tI.z + i2.w * tI.w;
        acc3 += r3.x * tR.x + r3.y * tR.y + r3.z * tR.z + r3.w * tR.w
              + i3.x * tI.x + i3.y * tI.y + i3.z * tI.z + i3.w * tI.w;

        n += 10; m += 6;
        if (m >= 25) { m -= 25; ++n; }
    }

    int wave = tid >> 6, lane = tid & 63;
    for (int off = 32; off > 0; off >>= 1) {
        acc0 += __shfl_down(acc0, off, 64);
        acc1 += __shfl_down(acc1, off, 64);
        acc2 += __shfl_down(acc2, off, 64);
        acc3 += __shfl_down(acc3, off, 64);
    }
    __shared__ float ws4[4][4];
    if (lane == 0) {
        ws4[wave][0] = acc0; ws4[wave][1] = acc1;
        ws4[wave][2] = acc2; ws4[wave][3] = acc3;
    }
    __syncthreads();

    __shared__ float sc;
    if (tid == 0) {
        float mx = -1e30f;
#pragma unroll
        for (int c = 0; c < 4; ++c) {
            float s = ws4[0][c] + ws4[1][c] + ws4[2][c] + ws4[3][c];
            mx = fmaxf(mx, s);
        }
        mx *= 1e15f;
        sc = 1.f / sqrtf(fmaxf(mx, 1.0f));
    }
    __syncthreads();
    if (tid < NRIS) {
        out[(size_t)b * DOUT + tid]        = sA[tid] * sc;
        out[(size_t)b * DOUT + NRIS + tid] = sB[tid] * sc;
    }
}

// ---------------------------------------------------------------------------
// launch
// ---------------------------------------------------------------------------
extern "C" void kernel_launch(void* const* d_in, const int* in_sizes, int n_in,
                              void* d_out, int out_size, void* d_ws, size_t ws_size,
                              hipStream_t stream)
{
    const float* sample1 = (const float*)d_in[0];
    const float* T_real  = (const float*)d_in[1];
    const float* T_imag  = (const float*)d_in[2];
    const float* W1 = (const float*)d_in[3];
    const float* b1 = (const float*)d_in[4];
    const float* W2 = (const float*)d_in[5];
    const float* b2 = (const float*)d_in[6];
    const float* W3 = (const float*)d_in[7];
    const float* b3 = (const float*)d_in[8];
    const float* W4 = (const float*)d_in[9];
    const float* b4 = (const float*)d_in[10];
    float* out = (float*)d_out;

    // ---- workspace carve-up (bytes) ----
    char* p = (char*)d_ws;
    auto take = [&](size_t bytes) { char* q = p; p += bytes; return q; };
    u16* Shi   = (u16*)take((size_t)BATCH * 320 * 2);
    u16* Slo   = (u16*)take((size_t)BATCH * 320 * 2);
    u16* BT1hi = (u16*)take((size_t)1024 * 320 * 2);
    u16* BT1lo = (u16*)take((size_t)1024 * 320 * 2);
    u16* BT2hi = (u16*)take((size_t)1024 * 1024 * 2);
    u16* BT2lo = (u16*)take((size_t)1024 * 1024 * 2);
    u16* BT3hi = (u16*)take((size_t)512 * 1024 * 2);
    u16* BT3lo = (u16*)take((size_t)512 * 1024 * 2);
    u16* BT4hi = (u16*)take((size_t)320 * 512 * 2);
    u16* BT4lo = (u16*)take((size_t)320 * 512 * 2);
    u16* h1hi  = (u16*)take((size_t)BATCH * 1024 * 2);
    u16* h1lo  = (u16*)take((size_t)BATCH * 1024 * 2);
    u16* h2hi  = (u16*)take((size_t)BATCH * 1024 * 2);
    u16* h2lo  = (u16*)take((size_t)BATCH * 1024 * 2);
    u16* h3hi  = (u16*)take((size_t)BATCH * 512 * 2);
    u16* h3lo  = (u16*)take((size_t)BATCH * 512 * 2);
    float* th1 = (float*)take((size_t)BATCH * TH1_LD * 4);

    dim3 blk(256);

    // ---- all input conversions in one launch ----
    convert_all_kernel<<<dim3(2552), blk, 0, stream>>>(
        sample1, W1, W2, W3, W4, Shi, Slo,
        BT1hi, BT1lo, BT2hi, BT2lo, BT3hi, BT3lo, BT4hi, BT4lo);

    // ---- MLP via split-bf16 MFMA, BK=64 (grids >= 320 blocks -> 2/CU) ----
    // G1: 303->1024, Kp=320 (nt=5). grid (32,16)=512.
    gemm_bf16x3<64, 64, true, true><<<dim3(32, 16), blk, 0, stream>>>(
        Shi, Slo, BT1hi, BT1lo, b1, 1024, nullptr, h1hi, h1lo, BATCH, 1024, 320);
    // G2: 1024->1024 (nt=16). grid (32,16)=512.
    gemm_bf16x3<64, 64, true, true><<<dim3(32, 16), blk, 0, stream>>>(
        h1hi, h1lo, BT2hi, BT2lo, b2, 1024, nullptr, h2hi, h2lo, BATCH, 1024, 1024);
    // G3: 1024->512 (nt=16). grid (64,8)=512.
    gemm_bf16x3<32, 64, true, true><<<dim3(64, 8), blk, 0, stream>>>(
        h2hi, h2lo, BT3hi, BT3lo, b3, 512, nullptr, h3hi, h3lo, BATCH, 512, 1024);
    // G4: 512->264 (N padded to 320, bias guarded, nt=8). grid (64,5)=320.
    gemm_bf16x3<32, 64, false, false><<<dim3(64, 5), blk, 0, stream>>>(
        h3hi, h3lo, BT4hi, BT4lo, b4, DOUT, th1, nullptr, nullptr, BATCH, TH1_LD, 512);

    // ---- theta path: prep + quad + finalize fused ----
    quadfin_kernel<<<dim3(BATCH), blk, 0, stream>>>(T_real, T_imag, th1, out);
}